// Round 3
// baseline (1352.700 us; speedup 1.0000x reference)
//
#include <hip/hip_runtime.h>
#include <hip/hip_bf16.h>

#define DEV_INLINE __device__ __forceinline__

using bf16x8 = __attribute__((ext_vector_type(8))) short;
using f32x4  = __attribute__((ext_vector_type(4))) float;

DEV_INLINE float leaky(float x, float s) { return x >= 0.f ? x : s * x; }
DEV_INLINE float bf2f(unsigned short u) { return __uint_as_float(((unsigned)u) << 16); }
DEV_INLINE unsigned short f2bf(float f) {           // round-to-nearest-even
  unsigned u = __float_as_uint(f);
  unsigned r = ((u >> 16) & 1u) + 0x7fffu;
  return (unsigned short)((u + r) >> 16);
}

// ---------------------------------------------------------------------------
// CSR build: stable two-pass counting sort, ZERO global atomics.
// Bucket = 256 consecutive dst nodes (NB = ceil(N/256), 391 for N=100000).
// NBLK = 256 scatter blocks, each owning a contiguous chunk of edges.
//  pass A: per-block LDS histogram of buckets -> blkcnt[blk][bucket] (coalesced)
//  pass B: single-block scan in (bucket,block)-major order -> blkoff + sbkt
//  pass C: re-read chunk, LDS cursors give each edge a unique slot in its
//          (block,bucket) subrange; write packed 4B (src<<8 | dst&255).
//  build:  per-bucket block sorts by node via LDS hist+scan, emits offs & csr.
// ---------------------------------------------------------------------------
#define BSHIFT 8      // 256 nodes per bucket
#define NBLK   256    // scatter blocks

__global__ __launch_bounds__(256) void csr_hist_kernel(
    const int* __restrict__ dst, int* __restrict__ blkcnt, int NB, int E) {
  __shared__ int hist[512];               // NB <= 512 (N <= 131072)
  int blk = blockIdx.x, t = threadIdx.x;
  for (int i = t; i < NB; i += 256) hist[i] = 0;
  __syncthreads();
  int chunk = (E + NBLK - 1) / NBLK;
  int e0 = blk * chunk;
  int e1 = e0 + chunk; if (e1 > E) e1 = E;
  for (int e = e0 + t; e < e1; e += 256)
    atomicAdd(&hist[dst[e] >> BSHIFT], 1);
  __syncthreads();
  for (int i = t; i < NB; i += 256)
    blkcnt[(size_t)blk * NB + i] = hist[i];
}

__global__ __launch_bounds__(1024) void csr_scan_kernel(
    const int* __restrict__ blkcnt, int* __restrict__ blkoff,
    int* __restrict__ sbkt, int NB) {
  __shared__ int sums[1024];
  int M = NB * NBLK;
  int t = threadIdx.x;
  int chunk = (M + 1023) / 1024;
  int lo = t * chunk;
  int hi = lo + chunk; if (hi > M) hi = M;
  int s = 0;
  for (int q = lo; q < hi; ++q) {            // q = bucket*NBLK + blk
    int b = q >> 8, blk = q & (NBLK - 1);
    s += blkcnt[(size_t)blk * NB + b];
  }
  sums[t] = s;
  __syncthreads();
  for (int off = 1; off < 1024; off <<= 1) {
    int v = (t >= off) ? sums[t - off] : 0;
    __syncthreads();
    sums[t] += v;
    __syncthreads();
  }
  int run = (t == 0) ? 0 : sums[t - 1];
  for (int q = lo; q < hi; ++q) {
    int b = q >> 8, blk = q & (NBLK - 1);
    if (blk == 0) sbkt[b] = run;
    blkoff[(size_t)blk * NB + b] = run;
    run += blkcnt[(size_t)blk * NB + b];
  }
  if (lo < M && hi == M) sbkt[NB] = run;     // == E
}

__global__ __launch_bounds__(256) void csr_scatter_kernel(
    const int* __restrict__ src, const int* __restrict__ dst,
    const int* __restrict__ blkoff, int* __restrict__ pairs, int NB, int E) {
  __shared__ int cur[512];
  int blk = blockIdx.x, t = threadIdx.x;
  for (int i = t; i < NB; i += 256) cur[i] = blkoff[(size_t)blk * NB + i];
  __syncthreads();
  int chunk = (E + NBLK - 1) / NBLK;
  int e0 = blk * chunk;
  int e1 = e0 + chunk; if (e1 > E) e1 = E;
  for (int e = e0 + t; e < e1; e += 256) {
    int d = dst[e];
    int pos = atomicAdd(&cur[d >> BSHIFT], 1);   // LDS atomic: fast, uncontended
    pairs[pos] = (src[e] << BSHIFT) | (d & 255);
  }
}

__global__ __launch_bounds__(256) void bkt_build_kernel(
    const int* __restrict__ sbkt, const int* __restrict__ pairs,
    int* __restrict__ offs, int* __restrict__ csr, int n_rows, int NB) {
  __shared__ int cnt[256];
  __shared__ int cur[256];
  int b = blockIdx.x, t = threadIdx.x;
  int start = sbkt[b];
  int end   = sbkt[b + 1];
  cnt[t] = 0;
  __syncthreads();
  for (int e = start + t; e < end; e += 256)
    atomicAdd(&cnt[pairs[e] & 255], 1);
  __syncthreads();
  // inclusive scan over 256 local node counts
  for (int off = 1; off < 256; off <<= 1) {
    int v = (t >= off) ? cnt[t - off] : 0;
    __syncthreads();
    cnt[t] += v;
    __syncthreads();
  }
  int ex = (t == 0) ? 0 : cnt[t - 1];
  cur[t] = start + ex;
  int node = (b << BSHIFT) + t;
  if (node < n_rows) offs[node] = start + ex;
  if (t == 0 && b == NB - 1) offs[n_rows] = end;   // == E
  __syncthreads();
  for (int e = start + t; e < end; e += 256) {
    int v = pairs[e];
    int pos = atomicAdd(&cur[v & 255], 1);         // LDS cursor
    csr[pos] = v >> BSHIFT;                        // ~33KB span: L2-resident
  }
}

// ---------------------------------------------------------------------------
// Weight swizzle for MFMA B-fragments (bf16):
// Wsw[((ks*CT + ct)*64 + L)*8 + j] = W[ks*32 + (L>>4)*8 + j][ct*16 + (L&15)]
// blockIdx.y selects which weight. All tiny; runs once per call.
// ---------------------------------------------------------------------------
__global__ __launch_bounds__(256) void swz_kernel(
    const float* __restrict__ w_des, const float* __restrict__ w_tw,
    const float* __restrict__ w_in, const float* __restrict__ g1_w,
    const float* __restrict__ g2_w, const float* __restrict__ w_o1,
    short* __restrict__ o_des, short* __restrict__ o_tw,
    short* __restrict__ o_in, short* __restrict__ o_g1,
    short* __restrict__ o_g2, short* __restrict__ o_o1) {
  const float* W; short* O; int K, COLS;
  switch (blockIdx.y) {
    case 0: W = w_des; O = o_des; K = 768; COLS = 32; break;
    case 1: W = w_tw;  O = o_tw;  K = 768; COLS = 32; break;
    case 2: W = w_in;  O = o_in;  K = 128; COLS = 128; break;
    case 3: W = g1_w;  O = o_g1;  K = 128; COLS = 128; break;
    case 4: W = g2_w;  O = o_g2;  K = 128; COLS = 128; break;
    default: W = w_o1; O = o_o1;  K = 128; COLS = 128; break;
  }
  int CT = COLS >> 4;
  int t = blockIdx.x * 256 + threadIdx.x;
  int total = (K >> 5) * CT * 64;
  if (t >= total) return;
  int L = t & 63;
  int rest = t >> 6;
  int ct = rest % CT;
  int ks = rest / CT;
  int kbase = ks * 32 + (L >> 4) * 8;
  int col = ct * 16 + (L & 15);
  #pragma unroll
  for (int j = 0; j < 8; ++j)
    O[t * 8 + j] = (short)f2bf(W[(size_t)(kbase + j) * COLS + col]);
}

// ---------------------------------------------------------------------------
// Encoder GEMMs via MFMA: [N,768]_f32 @ [768,32] -> x0 cols {0..31 | 32..63}
// block=256 (4 waves); wave = 16 rows x 32 cols; K-loop 24 x 32.
// Depth-2 register prefetch: keeps 2 iterations of A-loads in flight so the
// wave never stalls a full HBM latency per K-step (was latency-bound, VGPR=32
// showed zero staging regs).
// ---------------------------------------------------------------------------
__global__ __launch_bounds__(256) void enc_mfma_kernel(
    const float* __restrict__ des, const float* __restrict__ tweet,
    const short* __restrict__ wsw_des, const short* __restrict__ wsw_tw,
    const float* __restrict__ b_des, const float* __restrict__ b_tw,
    unsigned short* __restrict__ x0, int n_rows) {
  const float* A; const short* Wsw; const float* bias; int col_off;
  if (blockIdx.y == 0) { A = des;   Wsw = wsw_des; bias = b_des; col_off = 0; }
  else                 { A = tweet; Wsw = wsw_tw;  bias = b_tw;  col_off = 32; }
  int wv = threadIdx.x >> 6, lane = threadIdx.x & 63;
  int row0 = blockIdx.x * 64 + wv * 16;
  int rA = row0 + (lane & 15);
  int rc = rA < n_rows ? rA : (n_rows - 1);
  const float* arow = A + (size_t)rc * 768 + ((lane >> 4) * 8);
  f32x4 acc0 = {0.f, 0.f, 0.f, 0.f}, acc1 = {0.f, 0.f, 0.f, 0.f};

  // software pipeline, prefetch distance 2
  float4 p0a = *(const float4*)(arow + 0);
  float4 p0b = *(const float4*)(arow + 4);
  float4 p1a = *(const float4*)(arow + 32);
  float4 p1b = *(const float4*)(arow + 36);
  #pragma unroll
  for (int ks = 0; ks < 24; ++ks) {
    float4 c0 = p0a, c1 = p0b;
    p0a = p1a; p0b = p1b;
    if (ks + 2 < 24) {
      p1a = *(const float4*)(arow + (ks + 2) * 32);
      p1b = *(const float4*)(arow + (ks + 2) * 32 + 4);
    }
    bf16x8 af;
    af[0] = (short)f2bf(c0.x); af[1] = (short)f2bf(c0.y);
    af[2] = (short)f2bf(c0.z); af[3] = (short)f2bf(c0.w);
    af[4] = (short)f2bf(c1.x); af[5] = (short)f2bf(c1.y);
    af[6] = (short)f2bf(c1.z); af[7] = (short)f2bf(c1.w);
    bf16x8 b0 = *(const bf16x8*)&Wsw[(size_t)((ks * 2 + 0) * 64 + lane) * 8];
    bf16x8 b1 = *(const bf16x8*)&Wsw[(size_t)((ks * 2 + 1) * 64 + lane) * 8];
    acc0 = __builtin_amdgcn_mfma_f32_16x16x32_bf16(af, b0, acc0, 0, 0, 0);
    acc1 = __builtin_amdgcn_mfma_f32_16x16x32_bf16(af, b1, acc1, 0, 0, 0);
  }
  int quad = lane >> 4, cl = lane & 15;
  #pragma unroll
  for (int r = 0; r < 4; ++r) {
    int row = row0 + quad * 4 + r;
    if (row >= n_rows) continue;
    float v0 = leaky(acc0[r] + bias[cl], 0.01f);
    float v1 = leaky(acc1[r] + bias[16 + cl], 0.01f);
    x0[(size_t)row * 128 + col_off + cl]      = f2bf(v0);
    x0[(size_t)row * 128 + col_off + 16 + cl] = f2bf(v1);
  }
}

// ---------------------------------------------------------------------------
// Encoder small GEMMs: num_prop (K=6) -> cols 64..95, cat_prop (K=11) -> 96..127
// ---------------------------------------------------------------------------
__global__ __launch_bounds__(256) void enc_small_kernel(
    const float* __restrict__ np_, const float* __restrict__ cp,
    const float* __restrict__ w_np, const float* __restrict__ w_cp,
    const float* __restrict__ b_np, const float* __restrict__ b_cp,
    unsigned short* __restrict__ x0, int n_rows) {
  int gid = blockIdx.x * 256 + threadIdx.x;
  int node = gid >> 6;
  int c = gid & 63;
  if (node >= n_rows) return;
  float acc; int col;
  if (c < 32) {
    acc = b_np[c];
    #pragma unroll
    for (int k = 0; k < 6; ++k) acc += np_[(size_t)node * 6 + k] * w_np[k * 32 + c];
    col = 64 + c;
  } else {
    int cc = c - 32;
    acc = b_cp[cc];
    #pragma unroll
    for (int k = 0; k < 11; ++k) acc += cp[(size_t)node * 11 + k] * w_cp[k * 32 + cc];
    col = 96 + cc;
  }
  x0[(size_t)node * 128 + col] = f2bf(leaky(acc, 0.01f));
}

// ---------------------------------------------------------------------------
// Dense 128x128 via MFMA: Y[n][c] = act(sum_k X[n][k] W[k][c] + b[c])
// X bf16 [N][128], Wsw pre-swizzled bf16, Y bf16 [N][128].
// block=256 (4 waves); wave = 16 rows x 128 cols (8 tiles); K-loop 4 x 32.
// ---------------------------------------------------------------------------
template <bool LEAKY, bool BIAS>
__global__ __launch_bounds__(256) void dense_mfma_kernel(
    const unsigned short* __restrict__ X, const short* __restrict__ Wsw,
    const float* __restrict__ bias, unsigned short* __restrict__ Y, int n_rows) {
  int wv = threadIdx.x >> 6, lane = threadIdx.x & 63;
  int row0 = blockIdx.x * 64 + wv * 16;
  int rA = row0 + (lane & 15);
  int rc = rA < n_rows ? rA : (n_rows - 1);
  const unsigned short* xr = X + (size_t)rc * 128 + (lane >> 4) * 8;
  f32x4 acc[8] = {};
  #pragma unroll
  for (int ks = 0; ks < 4; ++ks) {
    bf16x8 af = *(const bf16x8*)(xr + ks * 32);
    #pragma unroll
    for (int ct = 0; ct < 8; ++ct) {
      bf16x8 bfr = *(const bf16x8*)&Wsw[(size_t)((ks * 8 + ct) * 64 + lane) * 8];
      acc[ct] = __builtin_amdgcn_mfma_f32_16x16x32_bf16(af, bfr, acc[ct], 0, 0, 0);
    }
  }
  int quad = lane >> 4, cl = lane & 15;
  #pragma unroll
  for (int r = 0; r < 4; ++r) {
    int row = row0 + quad * 4 + r;
    if (row >= n_rows) continue;
    #pragma unroll
    for (int ct = 0; ct < 8; ++ct) {
      float v = acc[ct][r];
      int col = ct * 16 + cl;
      if (BIAS) v += bias[col];
      if (LEAKY) v = leaky(v, 0.01f);
      Y[(size_t)row * 128 + col] = f2bf(v);
    }
  }
}

// ---------------------------------------------------------------------------
// Attention logit dots (h bf16): a_s[n][h], a_d[n][h]
// ---------------------------------------------------------------------------
template <int H>
__global__ __launch_bounds__(256) void att_dots_kernel(
    const ushort2* __restrict__ h2, const float* __restrict__ att_s,
    const float* __restrict__ att_d, float* __restrict__ a_s,
    float* __restrict__ a_d, int n_rows) {
  int wave = (blockIdx.x * 256 + threadIdx.x) >> 6;
  int lane = threadIdx.x & 63;
  if (wave >= n_rows) return;
  int c = lane * 2;
  ushort2 hv2 = h2[(size_t)wave * 64 + lane];
  float hx = bf2f(hv2.x), hy = bf2f(hv2.y);
  float2 sv = *(const float2*)&att_s[c];
  float2 dv = *(const float2*)&att_d[c];
  float ps = hx * sv.x + hy * sv.y;
  float pd = hx * dv.x + hy * dv.y;
  const int G = 64 / H;   // lanes per head group
  #pragma unroll
  for (int o = 1; o < G; o <<= 1) {
    ps += __shfl_xor(ps, o, 64);
    pd += __shfl_xor(pd, o, 64);
  }
  if ((lane & (G - 1)) == 0) {
    int head = lane / G;
    a_s[(size_t)wave * H + head] = ps;
    a_d[(size_t)wave * H + head] = pd;
  }
}

// ---------------------------------------------------------------------------
// GAT aggregation, online softmax, unroll-4 deferred rescale. Wave per dst.
// h bf16 [N][128] (as ushort2 rows of 64). Self-loop seeds the softmax.
// ---------------------------------------------------------------------------
template <int H>
__global__ __launch_bounds__(256) void agg_kernel(
    const ushort2* __restrict__ h2, const float* __restrict__ a_src,
    const float* __restrict__ a_dst, const int* __restrict__ offs,
    const int* __restrict__ csr_src, const float* __restrict__ bias,
    unsigned short* __restrict__ out, int n_rows) {
  int n = (blockIdx.x * 256 + threadIdx.x) >> 6;
  int lane = threadIdx.x & 63;
  if (n >= n_rows) return;
  int c = lane * 2;
  int head = (c * H) >> 7;

  float ad = a_dst[(size_t)n * H + head];
  float m = leaky(a_src[(size_t)n * H + head] + ad, 0.2f);
  float l = 1.0f;
  ushort2 hv = h2[(size_t)n * 64 + lane];
  float acc0 = bf2f(hv.x), acc1 = bf2f(hv.y);

  int e = offs[n], e1 = offs[n + 1];
  for (; e + 4 <= e1; e += 4) {
    int s0 = csr_src[e], s1 = csr_src[e + 1], s2 = csr_src[e + 2], s3 = csr_src[e + 3];
    float a0 = leaky(a_src[(size_t)s0 * H + head] + ad, 0.2f);
    float a1 = leaky(a_src[(size_t)s1 * H + head] + ad, 0.2f);
    float a2 = leaky(a_src[(size_t)s2 * H + head] + ad, 0.2f);
    float a3 = leaky(a_src[(size_t)s3 * H + head] + ad, 0.2f);
    ushort2 g0 = h2[(size_t)s0 * 64 + lane];
    ushort2 g1 = h2[(size_t)s1 * 64 + lane];
    ushort2 g2 = h2[(size_t)s2 * 64 + lane];
    ushort2 g3 = h2[(size_t)s3 * 64 + lane];
    float mn = fmaxf(fmaxf(fmaxf(a0, a1), fmaxf(a2, a3)), m);
    float sc = __expf(m - mn);
    float x0_ = __expf(a0 - mn), x1_ = __expf(a1 - mn);
    float x2_ = __expf(a2 - mn), x3_ = __expf(a3 - mn);
    l = l * sc + x0_ + x1_ + x2_ + x3_;
    acc0 = acc0 * sc + x0_ * bf2f(g0.x) + x1_ * bf2f(g1.x) + x2_ * bf2f(g2.x) + x3_ * bf2f(g3.x);
    acc1 = acc1 * sc + x0_ * bf2f(g0.y) + x1_ * bf2f(g1.y) + x2_ * bf2f(g2.y) + x3_ * bf2f(g3.y);
    m = mn;
  }
  for (; e < e1; ++e) {
    int s = csr_src[e];
    float a = leaky(a_src[(size_t)s * H + head] + ad, 0.2f);
    float mn = fmaxf(m, a);
    float sc = __expf(m - mn), ex = __expf(a - mn);
    ushort2 g = h2[(size_t)s * 64 + lane];
    l = l * sc + ex;
    acc0 = acc0 * sc + ex * bf2f(g.x);
    acc1 = acc1 * sc + ex * bf2f(g.y);
    m = mn;
  }
  float inv = 1.0f / (l + 1e-16f);
  out[(size_t)n * 128 + c]     = f2bf(acc0 * inv + bias[c]);
  out[(size_t)n * 128 + c + 1] = f2bf(acc1 * inv + bias[c + 1]);
}

// ---------------------------------------------------------------------------
// Final MLP tail: out[n][j] = t[n] . w_o2[:,j] + b_o2[j]  (t is bf16)
// ---------------------------------------------------------------------------
__global__ __launch_bounds__(256) void final2_kernel(
    const unsigned short* __restrict__ tt, const float* __restrict__ w,
    const float* __restrict__ b, float* __restrict__ out, int n_rows) {
  int gid = blockIdx.x * 256 + threadIdx.x;
  if (gid >= n_rows) return;
  const uint4* tp = (const uint4*)(tt + (size_t)gid * 128);
  float a0 = b[0], a1 = b[1];
  #pragma unroll 4
  for (int q = 0; q < 16; ++q) {
    uint4 raw = tp[q];
    unsigned vals[4] = {raw.x, raw.y, raw.z, raw.w};
    #pragma unroll
    for (int i = 0; i < 4; ++i) {
      float f0 = bf2f((unsigned short)(vals[i] & 0xffffu));
      float f1 = bf2f((unsigned short)(vals[i] >> 16));
      int k = q * 8 + i * 2;
      a0 += f0 * w[k * 2]     + f1 * w[(k + 1) * 2];
      a1 += f0 * w[k * 2 + 1] + f1 * w[(k + 1) * 2 + 1];
    }
  }
  out[(size_t)gid * 2 + 0] = a0;
  out[(size_t)gid * 2 + 1] = a1;
}

// ---------------------------------------------------------------------------
static inline size_t align256(size_t x) { return (x + 255) & ~(size_t)255; }

extern "C" void kernel_launch(void* const* d_in, const int* in_sizes, int n_in,
                              void* d_out, int out_size, void* d_ws, size_t ws_size,
                              hipStream_t stream) {
  const float* des      = (const float*)d_in[0];
  const float* tweet    = (const float*)d_in[1];
  const float* num_prop = (const float*)d_in[2];
  const float* cat_prop = (const float*)d_in[3];
  const int*   ei       = (const int*)d_in[4];
  const float* w_des = (const float*)d_in[6];
  const float* b_des = (const float*)d_in[7];
  const float* w_tw  = (const float*)d_in[8];
  const float* b_tw  = (const float*)d_in[9];
  const float* w_np  = (const float*)d_in[10];
  const float* b_np  = (const float*)d_in[11];
  const float* w_cp  = (const float*)d_in[12];
  const float* b_cp  = (const float*)d_in[13];
  const float* w_in  = (const float*)d_in[14];
  const float* b_in  = (const float*)d_in[15];
  const float* g1_w  = (const float*)d_in[16];
  const float* g1_as = (const float*)d_in[17];
  const float* g1_ad = (const float*)d_in[18];
  const float* g1_b  = (const float*)d_in[19];
  const float* g2_w  = (const float*)d_in[20];
  const float* g2_as = (const float*)d_in[21];
  const float* g2_ad = (const float*)d_in[22];
  const float* g2_b  = (const float*)d_in[23];
  const float* w_o1  = (const float*)d_in[24];
  const float* b_o1  = (const float*)d_in[25];
  const float* w_o2  = (const float*)d_in[26];
  const float* b_o2  = (const float*)d_in[27];

  const int N = in_sizes[0] / 768;
  const int E = in_sizes[4] / 2;
  const int* src = ei;
  const int* dst = ei + E;

  const int NB = (N + 255) >> BSHIFT;   // buckets of 256 nodes

  // ---- workspace layout (256B aligned segments) ----
  char* p = (char*)d_ws;
  unsigned short* bufA = (unsigned short*)p; p += align256((size_t)N * 128 * 2);
  unsigned short* bufB = (unsigned short*)p; p += align256((size_t)N * 128 * 2);
  float* as1 = (float*)p; p += align256((size_t)N * 4 * 4);
  float* ad1 = (float*)p; p += align256((size_t)N * 4 * 4);
  float* as2 = (float*)p; p += align256((size_t)N * 4);
  float* ad2 = (float*)p; p += align256((size_t)N * 4);
  int* offs = (int*)p; p += align256((size_t)(N + 1) * 4);
  int* csr  = (int*)p; p += align256((size_t)E * 4);
  short* sw_des = (short*)p; p += align256(768 * 32 * 2);
  short* sw_tw  = (short*)p; p += align256(768 * 32 * 2);
  short* sw_in  = (short*)p; p += align256(128 * 128 * 2);
  short* sw_g1  = (short*)p; p += align256(128 * 128 * 2);
  short* sw_g2  = (short*)p; p += align256(128 * 128 * 2);
  short* sw_o1  = (short*)p; p += align256(128 * 128 * 2);

  // CSR-build scratch aliases bufA/bufB: both are dead until the encoders /
  // first dense_mfma write them, which happens after the CSR build completes
  // (single stream => serialized).
  int* pairs = (int*)bufA;                       // E*4 <= N*256 bytes
  char* q = (char*)bufB;
  int* blkcnt = (int*)q; q += align256((size_t)NBLK * NB * 4);
  int* blkoff = (int*)q; q += align256((size_t)NBLK * NB * 4);
  int* sbkt   = (int*)q; q += align256((size_t)(NB + 1) * 4);

  // ---- weight swizzle (tiny) ----
  dim3 gswz(12, 6);
  swz_kernel<<<gswz, 256, 0, stream>>>(w_des, w_tw, w_in, g1_w, g2_w, w_o1,
                                       sw_des, sw_tw, sw_in, sw_g1, sw_g2, sw_o1);

  // ---- CSR build (no global atomics, no memset) ----
  csr_hist_kernel<<<NBLK, 256, 0, stream>>>(dst, blkcnt, NB, E);
  csr_scan_kernel<<<1, 1024, 0, stream>>>(blkcnt, blkoff, sbkt, NB);
  csr_scatter_kernel<<<NBLK, 256, 0, stream>>>(src, dst, blkoff, pairs, NB, E);
  bkt_build_kernel<<<NB, 256, 0, stream>>>(sbkt, pairs, offs, csr, N, NB);

  // ---- encoders -> bufA = x0 (bf16) ----
  dim3 genc((N + 63) / 64, 2);
  enc_mfma_kernel<<<genc, 256, 0, stream>>>(des, tweet, sw_des, sw_tw, b_des, b_tw, bufA, N);
  enc_small_kernel<<<((size_t)N * 64 + 255) / 256, 256, 0, stream>>>(
      num_prop, cat_prop, w_np, w_cp, b_np, b_cp, bufA, N);

  int gd = (N + 63) / 64;
  int gw = ((size_t)N * 64 + 255) / 256;   // one wave per node

  // ---- x = leaky(x0 @ w_in + b_in) -> bufB ----
  dense_mfma_kernel<true, true><<<gd, 256, 0, stream>>>(bufA, sw_in, b_in, bufB, N);

  // ---- GAT1 ----
  dense_mfma_kernel<false, false><<<gd, 256, 0, stream>>>(bufB, sw_g1, nullptr, bufA, N); // h1
  att_dots_kernel<4><<<gw, 256, 0, stream>>>((const ushort2*)bufA, g1_as, g1_ad, as1, ad1, N);
  agg_kernel<4><<<gw, 256, 0, stream>>>((const ushort2*)bufA, as1, ad1, offs, csr, g1_b, bufB, N); // x1

  // ---- GAT2 ----
  dense_mfma_kernel<false, false><<<gd, 256, 0, stream>>>(bufB, sw_g2, nullptr, bufA, N); // h2
  att_dots_kernel<1><<<gw, 256, 0, stream>>>((const ushort2*)bufA, g2_as, g2_ad, as2, ad2, N);
  agg_kernel<1><<<gw, 256, 0, stream>>>((const ushort2*)bufA, as2, ad2, offs, csr, g2_b, bufB, N); // x2

  // ---- output MLP ----
  dense_mfma_kernel<true, true><<<gd, 256, 0, stream>>>(bufB, sw_o1, b_o1, bufA, N); // t
  final2_kernel<<<(N + 255) / 256, 256, 0, stream>>>(bufA, w_o2, b_o2, (float*)d_out, N);
}

// Round 4
// 1311.323 us; speedup vs baseline: 1.0316x; 1.0316x over previous
//
#include <hip/hip_runtime.h>
#include <hip/hip_bf16.h>

#define DEV_INLINE __device__ __forceinline__

using bf16x8 = __attribute__((ext_vector_type(8))) short;
using f32x4  = __attribute__((ext_vector_type(4))) float;

DEV_INLINE float leaky(float x, float s) { return x >= 0.f ? x : s * x; }
DEV_INLINE float bf2f(unsigned short u) { return __uint_as_float(((unsigned)u) << 16); }
DEV_INLINE unsigned short f2bf(float f) {           // round-to-nearest-even
  unsigned u = __float_as_uint(f);
  unsigned r = ((u >> 16) & 1u) + 0x7fffu;
  return (unsigned short)((u + r) >> 16);
}
DEV_INLINE float red16(float v) {                   // sum over 16-lane group
  v += __shfl_xor(v, 1, 64); v += __shfl_xor(v, 2, 64);
  v += __shfl_xor(v, 4, 64); v += __shfl_xor(v, 8, 64);
  return v;
}

// ---------------------------------------------------------------------------
// CSR build: stable two-pass counting sort, ZERO global atomics.
// ---------------------------------------------------------------------------
#define BSHIFT 8      // 256 nodes per bucket
#define NBLK   256    // scatter blocks

__global__ __launch_bounds__(256) void csr_hist_kernel(
    const int* __restrict__ dst, int* __restrict__ blkcnt, int NB, int E) {
  __shared__ int hist[512];               // NB <= 512 (N <= 131072)
  int blk = blockIdx.x, t = threadIdx.x;
  for (int i = t; i < NB; i += 256) hist[i] = 0;
  __syncthreads();
  int chunk = (E + NBLK - 1) / NBLK;
  int e0 = blk * chunk;
  int e1 = e0 + chunk; if (e1 > E) e1 = E;
  for (int e = e0 + t; e < e1; e += 256)
    atomicAdd(&hist[dst[e] >> BSHIFT], 1);
  __syncthreads();
  for (int i = t; i < NB; i += 256)
    blkcnt[(size_t)blk * NB + i] = hist[i];
}

__global__ __launch_bounds__(1024) void csr_scan_kernel(
    const int* __restrict__ blkcnt, int* __restrict__ blkoff,
    int* __restrict__ sbkt, int NB) {
  __shared__ int sums[1024];
  int M = NB * NBLK;
  int t = threadIdx.x;
  int chunk = (M + 1023) / 1024;
  int lo = t * chunk;
  int hi = lo + chunk; if (hi > M) hi = M;
  int s = 0;
  for (int q = lo; q < hi; ++q) {            // q = bucket*NBLK + blk
    int b = q >> 8, blk = q & (NBLK - 1);
    s += blkcnt[(size_t)blk * NB + b];
  }
  sums[t] = s;
  __syncthreads();
  for (int off = 1; off < 1024; off <<= 1) {
    int v = (t >= off) ? sums[t - off] : 0;
    __syncthreads();
    sums[t] += v;
    __syncthreads();
  }
  int run = (t == 0) ? 0 : sums[t - 1];
  for (int q = lo; q < hi; ++q) {
    int b = q >> 8, blk = q & (NBLK - 1);
    if (blk == 0) sbkt[b] = run;
    blkoff[(size_t)blk * NB + b] = run;
    run += blkcnt[(size_t)blk * NB + b];
  }
  if (lo < M && hi == M) sbkt[NB] = run;     // == E
}

__global__ __launch_bounds__(256) void csr_scatter_kernel(
    const int* __restrict__ src, const int* __restrict__ dst,
    const int* __restrict__ blkoff, int* __restrict__ pairs, int NB, int E) {
  __shared__ int cur[512];
  int blk = blockIdx.x, t = threadIdx.x;
  for (int i = t; i < NB; i += 256) cur[i] = blkoff[(size_t)blk * NB + i];
  __syncthreads();
  int chunk = (E + NBLK - 1) / NBLK;
  int e0 = blk * chunk;
  int e1 = e0 + chunk; if (e1 > E) e1 = E;
  for (int e = e0 + t; e < e1; e += 256) {
    int d = dst[e];
    int pos = atomicAdd(&cur[d >> BSHIFT], 1);   // LDS atomic: fast, uncontended
    pairs[pos] = (src[e] << BSHIFT) | (d & 255);
  }
}

__global__ __launch_bounds__(256) void bkt_build_kernel(
    const int* __restrict__ sbkt, const int* __restrict__ pairs,
    int* __restrict__ offs, int* __restrict__ csr, int n_rows, int NB) {
  __shared__ int cnt[256];
  __shared__ int cur[256];
  int b = blockIdx.x, t = threadIdx.x;
  int start = sbkt[b];
  int end   = sbkt[b + 1];
  cnt[t] = 0;
  __syncthreads();
  for (int e = start + t; e < end; e += 256)
    atomicAdd(&cnt[pairs[e] & 255], 1);
  __syncthreads();
  for (int off = 1; off < 256; off <<= 1) {
    int v = (t >= off) ? cnt[t - off] : 0;
    __syncthreads();
    cnt[t] += v;
    __syncthreads();
  }
  int ex = (t == 0) ? 0 : cnt[t - 1];
  cur[t] = start + ex;
  int node = (b << BSHIFT) + t;
  if (node < n_rows) offs[node] = start + ex;
  if (t == 0 && b == NB - 1) offs[n_rows] = end;   // == E
  __syncthreads();
  for (int e = start + t; e < end; e += 256) {
    int v = pairs[e];
    int pos = atomicAdd(&cur[v & 255], 1);         // LDS cursor
    csr[pos] = v >> BSHIFT;                        // ~33KB span: L2-resident
  }
}

// ---------------------------------------------------------------------------
// Weight swizzle for MFMA B-fragments (bf16):
// Wsw[((ks*CT + ct)*64 + L)*8 + j] = W[ks*32 + (L>>4)*8 + j][ct*16 + (L&15)]
// ---------------------------------------------------------------------------
__global__ __launch_bounds__(256) void swz_kernel(
    const float* __restrict__ w_des, const float* __restrict__ w_tw,
    const float* __restrict__ w_in, const float* __restrict__ g1_w,
    const float* __restrict__ g2_w, const float* __restrict__ w_o1,
    short* __restrict__ o_des, short* __restrict__ o_tw,
    short* __restrict__ o_in, short* __restrict__ o_g1,
    short* __restrict__ o_g2, short* __restrict__ o_o1) {
  const float* W; short* O; int K, COLS;
  switch (blockIdx.y) {
    case 0: W = w_des; O = o_des; K = 768; COLS = 32; break;
    case 1: W = w_tw;  O = o_tw;  K = 768; COLS = 32; break;
    case 2: W = w_in;  O = o_in;  K = 128; COLS = 128; break;
    case 3: W = g1_w;  O = o_g1;  K = 128; COLS = 128; break;
    case 4: W = g2_w;  O = o_g2;  K = 128; COLS = 128; break;
    default: W = w_o1; O = o_o1;  K = 128; COLS = 128; break;
  }
  int CT = COLS >> 4;
  int t = blockIdx.x * 256 + threadIdx.x;
  int total = (K >> 5) * CT * 64;
  if (t >= total) return;
  int L = t & 63;
  int rest = t >> 6;
  int ct = rest % CT;
  int ks = rest / CT;
  int kbase = ks * 32 + (L >> 4) * 8;
  int col = ct * 16 + (L & 15);
  #pragma unroll
  for (int j = 0; j < 8; ++j)
    O[t * 8 + j] = (short)f2bf(W[(size_t)(kbase + j) * COLS + col]);
}

// ---------------------------------------------------------------------------
// Encoder GEMMs via MFMA: [N,768]_f32 @ [768,32] -> x0 cols {0..31 | 32..63}
// ---------------------------------------------------------------------------
__global__ __launch_bounds__(256) void enc_mfma_kernel(
    const float* __restrict__ des, const float* __restrict__ tweet,
    const short* __restrict__ wsw_des, const short* __restrict__ wsw_tw,
    const float* __restrict__ b_des, const float* __restrict__ b_tw,
    unsigned short* __restrict__ x0, int n_rows) {
  const float* A; const short* Wsw; const float* bias; int col_off;
  if (blockIdx.y == 0) { A = des;   Wsw = wsw_des; bias = b_des; col_off = 0; }
  else                 { A = tweet; Wsw = wsw_tw;  bias = b_tw;  col_off = 32; }
  int wv = threadIdx.x >> 6, lane = threadIdx.x & 63;
  int row0 = blockIdx.x * 64 + wv * 16;
  int rA = row0 + (lane & 15);
  int rc = rA < n_rows ? rA : (n_rows - 1);
  const float* arow = A + (size_t)rc * 768 + ((lane >> 4) * 8);
  f32x4 acc0 = {0.f, 0.f, 0.f, 0.f}, acc1 = {0.f, 0.f, 0.f, 0.f};

  float4 p0a = *(const float4*)(arow + 0);
  float4 p0b = *(const float4*)(arow + 4);
  float4 p1a = *(const float4*)(arow + 32);
  float4 p1b = *(const float4*)(arow + 36);
  #pragma unroll
  for (int ks = 0; ks < 24; ++ks) {
    float4 c0 = p0a, c1 = p0b;
    p0a = p1a; p0b = p1b;
    if (ks + 2 < 24) {
      p1a = *(const float4*)(arow + (ks + 2) * 32);
      p1b = *(const float4*)(arow + (ks + 2) * 32 + 4);
    }
    bf16x8 af;
    af[0] = (short)f2bf(c0.x); af[1] = (short)f2bf(c0.y);
    af[2] = (short)f2bf(c0.z); af[3] = (short)f2bf(c0.w);
    af[4] = (short)f2bf(c1.x); af[5] = (short)f2bf(c1.y);
    af[6] = (short)f2bf(c1.z); af[7] = (short)f2bf(c1.w);
    bf16x8 b0 = *(const bf16x8*)&Wsw[(size_t)((ks * 2 + 0) * 64 + lane) * 8];
    bf16x8 b1 = *(const bf16x8*)&Wsw[(size_t)((ks * 2 + 1) * 64 + lane) * 8];
    acc0 = __builtin_amdgcn_mfma_f32_16x16x32_bf16(af, b0, acc0, 0, 0, 0);
    acc1 = __builtin_amdgcn_mfma_f32_16x16x32_bf16(af, b1, acc1, 0, 0, 0);
  }
  int quad = lane >> 4, cl = lane & 15;
  #pragma unroll
  for (int r = 0; r < 4; ++r) {
    int row = row0 + quad * 4 + r;
    if (row >= n_rows) continue;
    float v0 = leaky(acc0[r] + bias[cl], 0.01f);
    float v1 = leaky(acc1[r] + bias[16 + cl], 0.01f);
    x0[(size_t)row * 128 + col_off + cl]      = f2bf(v0);
    x0[(size_t)row * 128 + col_off + 16 + cl] = f2bf(v1);
  }
}

// ---------------------------------------------------------------------------
// Encoder small GEMMs: num_prop (K=6) -> cols 64..95, cat_prop (K=11) -> 96..127
// ---------------------------------------------------------------------------
__global__ __launch_bounds__(256) void enc_small_kernel(
    const float* __restrict__ np_, const float* __restrict__ cp,
    const float* __restrict__ w_np, const float* __restrict__ w_cp,
    const float* __restrict__ b_np, const float* __restrict__ b_cp,
    unsigned short* __restrict__ x0, int n_rows) {
  int gid = blockIdx.x * 256 + threadIdx.x;
  int node = gid >> 6;
  int c = gid & 63;
  if (node >= n_rows) return;
  float acc; int col;
  if (c < 32) {
    acc = b_np[c];
    #pragma unroll
    for (int k = 0; k < 6; ++k) acc += np_[(size_t)node * 6 + k] * w_np[k * 32 + c];
    col = 64 + c;
  } else {
    int cc = c - 32;
    acc = b_cp[cc];
    #pragma unroll
    for (int k = 0; k < 11; ++k) acc += cp[(size_t)node * 11 + k] * w_cp[k * 32 + cc];
    col = 96 + cc;
  }
  x0[(size_t)node * 128 + col] = f2bf(leaky(acc, 0.01f));
}

// ---------------------------------------------------------------------------
// Fused: x = leaky(x0@w_in + b_in)  [kept in per-wave LDS, never global]
//        h1 = x @ g1_w              [written bf16]
//        a_s/a_d = att dots (H=4)   [in-register + 16-lane shfl reduce]
// Per-wave x-tile 16 rows x 128 bf16, XOR-swizzled (cb ^ ((row&7)<<4)) to
// break the stride-256B bank conflict on fragment reads. Tile is wave-private
// so no __syncthreads; compiler orders ds_write->ds_read via lgkmcnt.
// ---------------------------------------------------------------------------
__global__ __launch_bounds__(256) void h1_fused_kernel(
    const unsigned short* __restrict__ X, const short* __restrict__ sw_in,
    const float* __restrict__ b_in, const short* __restrict__ sw_g1,
    const float* __restrict__ att_s, const float* __restrict__ att_d,
    unsigned short* __restrict__ H1, float* __restrict__ a_s,
    float* __restrict__ a_d, int n_rows) {
  __shared__ char xt[4 * 4096];
  int wv = threadIdx.x >> 6, lane = threadIdx.x & 63;
  int row0 = blockIdx.x * 64 + wv * 16;
  int rA = row0 + (lane & 15);
  int rc = rA < n_rows ? rA : (n_rows - 1);
  const unsigned short* xr = X + (size_t)rc * 128 + (lane >> 4) * 8;
  int quad = lane >> 4, cl = lane & 15;
  char* xw = xt + wv * 4096;

  // GEMM1: x0 @ w_in
  f32x4 acc[8] = {};
  #pragma unroll
  for (int ks = 0; ks < 4; ++ks) {
    bf16x8 af = *(const bf16x8*)(xr + ks * 32);
    #pragma unroll
    for (int ct = 0; ct < 8; ++ct) {
      bf16x8 bfr = *(const bf16x8*)&sw_in[(size_t)((ks * 8 + ct) * 64 + lane) * 8];
      acc[ct] = __builtin_amdgcn_mfma_f32_16x16x32_bf16(af, bfr, acc[ct], 0, 0, 0);
    }
  }
  // bias + leaky, stash x-tile to LDS (swizzled)
  #pragma unroll
  for (int r = 0; r < 4; ++r) {
    int lr = quad * 4 + r;
    #pragma unroll
    for (int ct = 0; ct < 8; ++ct) {
      float v = leaky(acc[ct][r] + b_in[ct * 16 + cl], 0.01f);
      int cb = (ct * 32 + cl * 2) ^ ((lr & 7) << 4);
      *(unsigned short*)(xw + lr * 256 + cb) = f2bf(v);
    }
  }
  // GEMM2: x @ g1_w
  f32x4 acc2[8] = {};
  int lr2 = lane & 15;
  #pragma unroll
  for (int ks = 0; ks < 4; ++ks) {
    int cb0 = (((lane >> 4) * 16 + ks * 64)) ^ ((lr2 & 7) << 4);
    bf16x8 af = *(const bf16x8*)(xw + lr2 * 256 + cb0);
    #pragma unroll
    for (int ct = 0; ct < 8; ++ct) {
      bf16x8 bfr = *(const bf16x8*)&sw_g1[(size_t)((ks * 8 + ct) * 64 + lane) * 8];
      acc2[ct] = __builtin_amdgcn_mfma_f32_16x16x32_bf16(af, bfr, acc2[ct], 0, 0, 0);
    }
  }
  // epilogue: write h1 + att dots (head = col>>5 = ct>>1)
  float asv[8], adv[8];
  #pragma unroll
  for (int ct = 0; ct < 8; ++ct) {
    int idx = (ct >> 1) * 32 + (ct & 1) * 16 + cl;
    asv[ct] = att_s[idx];
    adv[ct] = att_d[idx];
  }
  #pragma unroll
  for (int r = 0; r < 4; ++r) {
    int row = row0 + quad * 4 + r;
    bool ok = row < n_rows;
    if (ok) {
      #pragma unroll
      for (int ct = 0; ct < 8; ++ct)
        H1[(size_t)row * 128 + ct * 16 + cl] = f2bf(acc2[ct][r]);
    }
    #pragma unroll
    for (int h = 0; h < 4; ++h) {
      float ps = acc2[2 * h][r] * asv[2 * h] + acc2[2 * h + 1][r] * asv[2 * h + 1];
      float pd = acc2[2 * h][r] * adv[2 * h] + acc2[2 * h + 1][r] * adv[2 * h + 1];
      ps = red16(ps); pd = red16(pd);
      if (ok && cl == 0) {
        a_s[(size_t)row * 4 + h] = ps;
        a_d[(size_t)row * 4 + h] = pd;
      }
    }
  }
}

// ---------------------------------------------------------------------------
// Fused: h2 = x1 @ g2_w (no bias/act) + att dots (H=1)
// ---------------------------------------------------------------------------
__global__ __launch_bounds__(256) void h2_fused_kernel(
    const unsigned short* __restrict__ X, const short* __restrict__ Wsw,
    const float* __restrict__ att_s, const float* __restrict__ att_d,
    unsigned short* __restrict__ H2, float* __restrict__ a_s,
    float* __restrict__ a_d, int n_rows) {
  int wv = threadIdx.x >> 6, lane = threadIdx.x & 63;
  int row0 = blockIdx.x * 64 + wv * 16;
  int rA = row0 + (lane & 15);
  int rc = rA < n_rows ? rA : (n_rows - 1);
  const unsigned short* xr = X + (size_t)rc * 128 + (lane >> 4) * 8;
  int quad = lane >> 4, cl = lane & 15;
  f32x4 acc[8] = {};
  #pragma unroll
  for (int ks = 0; ks < 4; ++ks) {
    bf16x8 af = *(const bf16x8*)(xr + ks * 32);
    #pragma unroll
    for (int ct = 0; ct < 8; ++ct) {
      bf16x8 bfr = *(const bf16x8*)&Wsw[(size_t)((ks * 8 + ct) * 64 + lane) * 8];
      acc[ct] = __builtin_amdgcn_mfma_f32_16x16x32_bf16(af, bfr, acc[ct], 0, 0, 0);
    }
  }
  float asv[8], adv[8];
  #pragma unroll
  for (int ct = 0; ct < 8; ++ct) {
    asv[ct] = att_s[ct * 16 + cl];
    adv[ct] = att_d[ct * 16 + cl];
  }
  #pragma unroll
  for (int r = 0; r < 4; ++r) {
    int row = row0 + quad * 4 + r;
    bool ok = row < n_rows;
    float ps = 0.f, pd = 0.f;
    #pragma unroll
    for (int ct = 0; ct < 8; ++ct) {
      if (ok) H2[(size_t)row * 128 + ct * 16 + cl] = f2bf(acc[ct][r]);
      ps += acc[ct][r] * asv[ct];
      pd += acc[ct][r] * adv[ct];
    }
    ps = red16(ps); pd = red16(pd);
    if (ok && cl == 0) { a_s[row] = ps; a_d[row] = pd; }
  }
}

// ---------------------------------------------------------------------------
// Fused: t = leaky(x2 @ w_o1 + b_o1)  [registers only]
//        out = t @ w_o2 + b_o2        [128x2 dot + 16-lane reduce]
// ---------------------------------------------------------------------------
__global__ __launch_bounds__(256) void out_fused_kernel(
    const unsigned short* __restrict__ X, const short* __restrict__ Wsw,
    const float* __restrict__ bias, const float* __restrict__ w_o2,
    const float* __restrict__ b_o2, float* __restrict__ out, int n_rows) {
  int wv = threadIdx.x >> 6, lane = threadIdx.x & 63;
  int row0 = blockIdx.x * 64 + wv * 16;
  int rA = row0 + (lane & 15);
  int rc = rA < n_rows ? rA : (n_rows - 1);
  const unsigned short* xr = X + (size_t)rc * 128 + (lane >> 4) * 8;
  int quad = lane >> 4, cl = lane & 15;
  f32x4 acc[8] = {};
  #pragma unroll
  for (int ks = 0; ks < 4; ++ks) {
    bf16x8 af = *(const bf16x8*)(xr + ks * 32);
    #pragma unroll
    for (int ct = 0; ct < 8; ++ct) {
      bf16x8 bfr = *(const bf16x8*)&Wsw[(size_t)((ks * 8 + ct) * 64 + lane) * 8];
      acc[ct] = __builtin_amdgcn_mfma_f32_16x16x32_bf16(af, bfr, acc[ct], 0, 0, 0);
    }
  }
  float w0v[8], w1v[8], bv[8];
  #pragma unroll
  for (int ct = 0; ct < 8; ++ct) {
    int col = ct * 16 + cl;
    w0v[ct] = w_o2[col * 2 + 0];
    w1v[ct] = w_o2[col * 2 + 1];
    bv[ct]  = bias[col];
  }
  float ob0 = b_o2[0], ob1 = b_o2[1];
  #pragma unroll
  for (int r = 0; r < 4; ++r) {
    int row = row0 + quad * 4 + r;
    bool ok = row < n_rows;
    float p0 = 0.f, p1 = 0.f;
    #pragma unroll
    for (int ct = 0; ct < 8; ++ct) {
      float t = leaky(acc[ct][r] + bv[ct], 0.01f);
      p0 += t * w0v[ct];
      p1 += t * w1v[ct];
    }
    p0 = red16(p0); p1 = red16(p1);
    if (ok && cl == 0) {
      out[(size_t)row * 2 + 0] = p0 + ob0;
      out[(size_t)row * 2 + 1] = p1 + ob1;
    }
  }
}

// ---------------------------------------------------------------------------
// GAT aggregation, online softmax, unroll-4 deferred rescale. Wave per dst.
// ---------------------------------------------------------------------------
template <int H>
__global__ __launch_bounds__(256) void agg_kernel(
    const ushort2* __restrict__ h2, const float* __restrict__ a_src,
    const float* __restrict__ a_dst, const int* __restrict__ offs,
    const int* __restrict__ csr_src, const float* __restrict__ bias,
    unsigned short* __restrict__ out, int n_rows) {
  int n = (blockIdx.x * 256 + threadIdx.x) >> 6;
  int lane = threadIdx.x & 63;
  if (n >= n_rows) return;
  int c = lane * 2;
  int head = (c * H) >> 7;

  float ad = a_dst[(size_t)n * H + head];
  float m = leaky(a_src[(size_t)n * H + head] + ad, 0.2f);
  float l = 1.0f;
  ushort2 hv = h2[(size_t)n * 64 + lane];
  float acc0 = bf2f(hv.x), acc1 = bf2f(hv.y);

  int e = offs[n], e1 = offs[n + 1];
  for (; e + 4 <= e1; e += 4) {
    int s0 = csr_src[e], s1 = csr_src[e + 1], s2 = csr_src[e + 2], s3 = csr_src[e + 3];
    float a0 = leaky(a_src[(size_t)s0 * H + head] + ad, 0.2f);
    float a1 = leaky(a_src[(size_t)s1 * H + head] + ad, 0.2f);
    float a2 = leaky(a_src[(size_t)s2 * H + head] + ad, 0.2f);
    float a3 = leaky(a_src[(size_t)s3 * H + head] + ad, 0.2f);
    ushort2 g0 = h2[(size_t)s0 * 64 + lane];
    ushort2 g1 = h2[(size_t)s1 * 64 + lane];
    ushort2 g2 = h2[(size_t)s2 * 64 + lane];
    ushort2 g3 = h2[(size_t)s3 * 64 + lane];
    float mn = fmaxf(fmaxf(fmaxf(a0, a1), fmaxf(a2, a3)), m);
    float sc = __expf(m - mn);
    float x0_ = __expf(a0 - mn), x1_ = __expf(a1 - mn);
    float x2_ = __expf(a2 - mn), x3_ = __expf(a3 - mn);
    l = l * sc + x0_ + x1_ + x2_ + x3_;
    acc0 = acc0 * sc + x0_ * bf2f(g0.x) + x1_ * bf2f(g1.x) + x2_ * bf2f(g2.x) + x3_ * bf2f(g3.x);
    acc1 = acc1 * sc + x0_ * bf2f(g0.y) + x1_ * bf2f(g1.y) + x2_ * bf2f(g2.y) + x3_ * bf2f(g3.y);
    m = mn;
  }
  for (; e < e1; ++e) {
    int s = csr_src[e];
    float a = leaky(a_src[(size_t)s * H + head] + ad, 0.2f);
    float mn = fmaxf(m, a);
    float sc = __expf(m - mn), ex = __expf(a - mn);
    ushort2 g = h2[(size_t)s * 64 + lane];
    l = l * sc + ex;
    acc0 = acc0 * sc + ex * bf2f(g.x);
    acc1 = acc1 * sc + ex * bf2f(g.y);
    m = mn;
  }
  float inv = 1.0f / (l + 1e-16f);
  out[(size_t)n * 128 + c]     = f2bf(acc0 * inv + bias[c]);
  out[(size_t)n * 128 + c + 1] = f2bf(acc1 * inv + bias[c + 1]);
}

// ---------------------------------------------------------------------------
static inline size_t align256(size_t x) { return (x + 255) & ~(size_t)255; }

extern "C" void kernel_launch(void* const* d_in, const int* in_sizes, int n_in,
                              void* d_out, int out_size, void* d_ws, size_t ws_size,
                              hipStream_t stream) {
  const float* des      = (const float*)d_in[0];
  const float* tweet    = (const float*)d_in[1];
  const float* num_prop = (const float*)d_in[2];
  const float* cat_prop = (const float*)d_in[3];
  const int*   ei       = (const int*)d_in[4];
  const float* w_des = (const float*)d_in[6];
  const float* b_des = (const float*)d_in[7];
  const float* w_tw  = (const float*)d_in[8];
  const float* b_tw  = (const float*)d_in[9];
  const float* w_np  = (const float*)d_in[10];
  const float* b_np  = (const float*)d_in[11];
  const float* w_cp  = (const float*)d_in[12];
  const float* b_cp  = (const float*)d_in[13];
  const float* w_in  = (const float*)d_in[14];
  const float* b_in  = (const float*)d_in[15];
  const float* g1_w  = (const float*)d_in[16];
  const float* g1_as = (const float*)d_in[17];
  const float* g1_ad = (const float*)d_in[18];
  const float* g1_b  = (const float*)d_in[19];
  const float* g2_w  = (const float*)d_in[20];
  const float* g2_as = (const float*)d_in[21];
  const float* g2_ad = (const float*)d_in[22];
  const float* g2_b  = (const float*)d_in[23];
  const float* w_o1  = (const float*)d_in[24];
  const float* b_o1  = (const float*)d_in[25];
  const float* w_o2  = (const float*)d_in[26];
  const float* b_o2  = (const float*)d_in[27];

  const int N = in_sizes[0] / 768;
  const int E = in_sizes[4] / 2;
  const int* src = ei;
  const int* dst = ei + E;

  const int NB = (N + 255) >> BSHIFT;   // buckets of 256 nodes

  // ---- workspace layout (256B aligned segments) ----
  char* p = (char*)d_ws;
  unsigned short* bufA = (unsigned short*)p; p += align256((size_t)N * 128 * 2);
  unsigned short* bufB = (unsigned short*)p; p += align256((size_t)N * 128 * 2);
  float* as1 = (float*)p; p += align256((size_t)N * 4 * 4);
  float* ad1 = (float*)p; p += align256((size_t)N * 4 * 4);
  float* as2 = (float*)p; p += align256((size_t)N * 4);
  float* ad2 = (float*)p; p += align256((size_t)N * 4);
  int* offs = (int*)p; p += align256((size_t)(N + 1) * 4);
  int* csr  = (int*)p; p += align256((size_t)E * 4);
  short* sw_des = (short*)p; p += align256(768 * 32 * 2);
  short* sw_tw  = (short*)p; p += align256(768 * 32 * 2);
  short* sw_in  = (short*)p; p += align256(128 * 128 * 2);
  short* sw_g1  = (short*)p; p += align256(128 * 128 * 2);
  short* sw_g2  = (short*)p; p += align256(128 * 128 * 2);
  short* sw_o1  = (short*)p; p += align256(128 * 128 * 2);

  // CSR-build scratch aliases bufA/bufB (dead until encoders write them).
  int* pairs = (int*)bufA;                       // E*4 <= N*256 bytes
  char* q = (char*)bufB;
  int* blkcnt = (int*)q; q += align256((size_t)NBLK * NB * 4);
  int* blkoff = (int*)q; q += align256((size_t)NBLK * NB * 4);
  int* sbkt   = (int*)q; q += align256((size_t)(NB + 1) * 4);

  // ---- weight swizzle (tiny) ----
  dim3 gswz(12, 6);
  swz_kernel<<<gswz, 256, 0, stream>>>(w_des, w_tw, w_in, g1_w, g2_w, w_o1,
                                       sw_des, sw_tw, sw_in, sw_g1, sw_g2, sw_o1);

  // ---- CSR build (no global atomics, no memset) ----
  csr_hist_kernel<<<NBLK, 256, 0, stream>>>(dst, blkcnt, NB, E);
  csr_scan_kernel<<<1, 1024, 0, stream>>>(blkcnt, blkoff, sbkt, NB);
  csr_scatter_kernel<<<NBLK, 256, 0, stream>>>(src, dst, blkoff, pairs, NB, E);
  bkt_build_kernel<<<NB, 256, 0, stream>>>(sbkt, pairs, offs, csr, N, NB);

  // ---- encoders -> bufA = x0 (bf16) ----
  dim3 genc((N + 63) / 64, 2);
  enc_mfma_kernel<<<genc, 256, 0, stream>>>(des, tweet, sw_des, sw_tw, b_des, b_tw, bufA, N);
  enc_small_kernel<<<((size_t)N * 64 + 255) / 256, 256, 0, stream>>>(
      num_prop, cat_prop, w_np, w_cp, b_np, b_cp, bufA, N);

  int gd = (N + 63) / 64;
  int gw = ((size_t)N * 64 + 255) / 256;   // one wave per node

  // ---- GAT1: x = leaky(x0@w_in+b_in) -> h1 = x@g1_w (+dots) -> bufB ----
  h1_fused_kernel<<<gd, 256, 0, stream>>>(bufA, sw_in, b_in, sw_g1,
                                          g1_as, g1_ad, bufB, as1, ad1, N);
  agg_kernel<4><<<gw, 256, 0, stream>>>((const ushort2*)bufB, as1, ad1, offs, csr, g1_b, bufA, N); // x1

  // ---- GAT2: h2 = x1@g2_w (+dots) -> bufB ----
  h2_fused_kernel<<<gd, 256, 0, stream>>>(bufA, sw_g2, g2_as, g2_ad, bufB, as2, ad2, N);
  agg_kernel<1><<<gw, 256, 0, stream>>>((const ushort2*)bufB, as2, ad2, offs, csr, g2_b, bufA, N); // x2

  // ---- output MLP: t = leaky(x2@w_o1+b_o1); out = t@w_o2+b_o2 ----
  out_fused_kernel<<<gd, 256, 0, stream>>>(bufA, sw_o1, b_o1, w_o2, b_o2, (float*)d_out, N);
}

// Round 5
// 1284.198 us; speedup vs baseline: 1.0533x; 1.0211x over previous
//
#include <hip/hip_runtime.h>
#include <hip/hip_bf16.h>

#define DEV_INLINE __device__ __forceinline__

using bf16x8 = __attribute__((ext_vector_type(8))) short;
using f32x4  = __attribute__((ext_vector_type(4))) float;

DEV_INLINE float leaky(float x, float s) { return x >= 0.f ? x : s * x; }
DEV_INLINE float bf2f(unsigned short u) { return __uint_as_float(((unsigned)u) << 16); }
DEV_INLINE unsigned short f2bf(float f) {           // round-to-nearest-even
  unsigned u = __float_as_uint(f);
  unsigned r = ((u >> 16) & 1u) + 0x7fffu;
  return (unsigned short)((u + r) >> 16);
}
DEV_INLINE float red16(float v) {                   // sum over 16-lane group
  v += __shfl_xor(v, 1, 64); v += __shfl_xor(v, 2, 64);
  v += __shfl_xor(v, 4, 64); v += __shfl_xor(v, 8, 64);
  return v;
}

// ---------------------------------------------------------------------------
// CSR build: stable two-pass counting sort, ZERO global atomics.
// ---------------------------------------------------------------------------
#define BSHIFT 8      // 256 nodes per bucket
#define NBLK   256    // scatter blocks

__global__ __launch_bounds__(256) void csr_hist_kernel(
    const int* __restrict__ dst, int* __restrict__ blkcnt, int NB, int E) {
  __shared__ int hist[512];               // NB <= 512 (N <= 131072)
  int blk = blockIdx.x, t = threadIdx.x;
  for (int i = t; i < NB; i += 256) hist[i] = 0;
  __syncthreads();
  int chunk = (E + NBLK - 1) / NBLK;
  int e0 = blk * chunk;
  int e1 = e0 + chunk; if (e1 > E) e1 = E;
  for (int e = e0 + t; e < e1; e += 256)
    atomicAdd(&hist[dst[e] >> BSHIFT], 1);
  __syncthreads();
  for (int i = t; i < NB; i += 256)
    blkcnt[(size_t)blk * NB + i] = hist[i];
}

__global__ __launch_bounds__(1024) void csr_scan_kernel(
    const int* __restrict__ blkcnt, int* __restrict__ blkoff,
    int* __restrict__ sbkt, int NB) {
  __shared__ int sums[1024];
  int M = NB * NBLK;
  int t = threadIdx.x;
  int chunk = (M + 1023) / 1024;
  int lo = t * chunk;
  int hi = lo + chunk; if (hi > M) hi = M;
  int s = 0;
  for (int q = lo; q < hi; ++q) {            // q = bucket*NBLK + blk
    int b = q >> 8, blk = q & (NBLK - 1);
    s += blkcnt[(size_t)blk * NB + b];
  }
  sums[t] = s;
  __syncthreads();
  for (int off = 1; off < 1024; off <<= 1) {
    int v = (t >= off) ? sums[t - off] : 0;
    __syncthreads();
    sums[t] += v;
    __syncthreads();
  }
  int run = (t == 0) ? 0 : sums[t - 1];
  for (int q = lo; q < hi; ++q) {
    int b = q >> 8, blk = q & (NBLK - 1);
    if (blk == 0) sbkt[b] = run;
    blkoff[(size_t)blk * NB + b] = run;
    run += blkcnt[(size_t)blk * NB + b];
  }
  if (lo < M && hi == M) sbkt[NB] = run;     // == E
}

__global__ __launch_bounds__(256) void csr_scatter_kernel(
    const int* __restrict__ src, const int* __restrict__ dst,
    const int* __restrict__ blkoff, int* __restrict__ pairs, int NB, int E) {
  __shared__ int cur[512];
  int blk = blockIdx.x, t = threadIdx.x;
  for (int i = t; i < NB; i += 256) cur[i] = blkoff[(size_t)blk * NB + i];
  __syncthreads();
  int chunk = (E + NBLK - 1) / NBLK;
  int e0 = blk * chunk;
  int e1 = e0 + chunk; if (e1 > E) e1 = E;
  for (int e = e0 + t; e < e1; e += 256) {
    int d = dst[e];
    int pos = atomicAdd(&cur[d >> BSHIFT], 1);   // LDS atomic: fast, uncontended
    pairs[pos] = (src[e] << BSHIFT) | (d & 255);
  }
}

__global__ __launch_bounds__(256) void bkt_build_kernel(
    const int* __restrict__ sbkt, const int* __restrict__ pairs,
    int* __restrict__ offs, int* __restrict__ csr, int n_rows, int NB) {
  __shared__ int cnt[256];
  __shared__ int cur[256];
  int b = blockIdx.x, t = threadIdx.x;
  int start = sbkt[b];
  int end   = sbkt[b + 1];
  cnt[t] = 0;
  __syncthreads();
  for (int e = start + t; e < end; e += 256)
    atomicAdd(&cnt[pairs[e] & 255], 1);
  __syncthreads();
  for (int off = 1; off < 256; off <<= 1) {
    int v = (t >= off) ? cnt[t - off] : 0;
    __syncthreads();
    cnt[t] += v;
    __syncthreads();
  }
  int ex = (t == 0) ? 0 : cnt[t - 1];
  cur[t] = start + ex;
  int node = (b << BSHIFT) + t;
  if (node < n_rows) offs[node] = start + ex;
  if (t == 0 && b == NB - 1) offs[n_rows] = end;   // == E
  __syncthreads();
  for (int e = start + t; e < end; e += 256) {
    int v = pairs[e];
    int pos = atomicAdd(&cur[v & 255], 1);         // LDS cursor
    csr[pos] = v >> BSHIFT;                        // ~33KB span: L2-resident
  }
}

// ---------------------------------------------------------------------------
// Weight swizzle for MFMA B-fragments (bf16):
// Wsw[((ks*CT + ct)*64 + L)*8 + j] = W[ks*32 + (L>>4)*8 + j][ct*16 + (L&15)]
// ---------------------------------------------------------------------------
__global__ __launch_bounds__(256) void swz_kernel(
    const float* __restrict__ w_des, const float* __restrict__ w_tw,
    const float* __restrict__ w_in, const float* __restrict__ g1_w,
    const float* __restrict__ g2_w, const float* __restrict__ w_o1,
    short* __restrict__ o_des, short* __restrict__ o_tw,
    short* __restrict__ o_in, short* __restrict__ o_g1,
    short* __restrict__ o_g2, short* __restrict__ o_o1) {
  const float* W; short* O; int K, COLS;
  switch (blockIdx.y) {
    case 0: W = w_des; O = o_des; K = 768; COLS = 32; break;
    case 1: W = w_tw;  O = o_tw;  K = 768; COLS = 32; break;
    case 2: W = w_in;  O = o_in;  K = 128; COLS = 128; break;
    case 3: W = g1_w;  O = o_g1;  K = 128; COLS = 128; break;
    case 4: W = g2_w;  O = o_g2;  K = 128; COLS = 128; break;
    default: W = w_o1; O = o_o1;  K = 128; COLS = 128; break;
  }
  int CT = COLS >> 4;
  int t = blockIdx.x * 256 + threadIdx.x;
  int total = (K >> 5) * CT * 64;
  if (t >= total) return;
  int L = t & 63;
  int rest = t >> 6;
  int ct = rest % CT;
  int ks = rest / CT;
  int kbase = ks * 32 + (L >> 4) * 8;
  int col = ct * 16 + (L & 15);
  #pragma unroll
  for (int j = 0; j < 8; ++j)
    O[t * 8 + j] = (short)f2bf(W[(size_t)(kbase + j) * COLS + col]);
}

// ---------------------------------------------------------------------------
// Encoder GEMMs via LDS-staged MFMA: [N,768]_f32 @ [768,32] -> x0 cols
// {0..31 | 32..63} (blockIdx.y picks des/tweet).
// Block = 32 rows of A = 96KB CONTIGUOUS f32, staged coalesced (float4,
// linear walk) -> bf16 LDS tile [32][768] with 16B XOR swizzle
// (byte ^ (row&7)<<4) to kill the stride-1536B bank conflict on ds_read_b128.
// 4 waves: (wv>>1) = row-half, (wv&1) = 16-col tile. DRAM sees only long
// sequential bursts (fix for 3.35 TB/s strided-stream ceiling seen in r3/r4).
// ---------------------------------------------------------------------------
__global__ __launch_bounds__(256) void enc_lds_kernel(
    const float* __restrict__ des, const float* __restrict__ tweet,
    const short* __restrict__ wsw_des, const short* __restrict__ wsw_tw,
    const float* __restrict__ b_des, const float* __restrict__ b_tw,
    unsigned short* __restrict__ x0, int n_rows) {
  const float* A; const short* Wsw; const float* bias; int col_off;
  if (blockIdx.y == 0) { A = des;   Wsw = wsw_des; bias = b_des; col_off = 0; }
  else                 { A = tweet; Wsw = wsw_tw;  bias = b_tw;  col_off = 32; }
  __shared__ char xt[32 * 1536];          // 48KB bf16 tile [32][768]
  int t = threadIdx.x;
  int row0 = blockIdx.x * 32;

  // ---- stage: 32 rows x 768 f32 = 6144 float4, 24 per thread, linear ----
  #pragma unroll
  for (int i = 0; i < 24; ++i) {
    int f = t + i * 256;                  // float4 index in tile
    int row = f / 192;                    // 192 float4 per row
    int c4 = f - row * 192;
    int gr = row0 + row;
    int grc = gr < n_rows ? gr : (n_rows - 1);
    float4 v = *(const float4*)(A + (size_t)grc * 768 + c4 * 4);
    ushort4 b;
    b.x = f2bf(v.x); b.y = f2bf(v.y); b.z = f2bf(v.z); b.w = f2bf(v.w);
    *(ushort4*)(xt + row * 1536 + ((c4 * 8) ^ ((row & 7) << 4))) = b;
  }
  __syncthreads();

  // ---- compute: wave = 16 rows x 16 cols, K-loop 24 x 32 ----
  int wv = t >> 6, lane = t & 63;
  int rh = wv >> 1, ct = wv & 1;
  int quad = lane >> 4, cl = lane & 15;
  int r_loc = rh * 16 + cl;               // A-fragment row (local)
  const char* arow = xt + r_loc * 1536;
  int sw = (r_loc & 7) << 4;
  f32x4 acc = {0.f, 0.f, 0.f, 0.f};
  #pragma unroll
  for (int ks = 0; ks < 24; ++ks) {
    bf16x8 af = *(const bf16x8*)(arow + ((ks * 64 + quad * 16) ^ sw));
    bf16x8 bfr = *(const bf16x8*)&Wsw[(size_t)((ks * 2 + ct) * 64 + lane) * 8];
    acc = __builtin_amdgcn_mfma_f32_16x16x32_bf16(af, bfr, acc, 0, 0, 0);
  }
  float bv = bias[ct * 16 + cl];
  #pragma unroll
  for (int r = 0; r < 4; ++r) {
    int row = row0 + rh * 16 + quad * 4 + r;
    if (row >= n_rows) continue;
    float v = leaky(acc[r] + bv, 0.01f);
    x0[(size_t)row * 128 + col_off + ct * 16 + cl] = f2bf(v);
  }
}

// ---------------------------------------------------------------------------
// Encoder small GEMMs: num_prop (K=6) -> cols 64..95, cat_prop (K=11) -> 96..127
// ---------------------------------------------------------------------------
__global__ __launch_bounds__(256) void enc_small_kernel(
    const float* __restrict__ np_, const float* __restrict__ cp,
    const float* __restrict__ w_np, const float* __restrict__ w_cp,
    const float* __restrict__ b_np, const float* __restrict__ b_cp,
    unsigned short* __restrict__ x0, int n_rows) {
  int gid = blockIdx.x * 256 + threadIdx.x;
  int node = gid >> 6;
  int c = gid & 63;
  if (node >= n_rows) return;
  float acc; int col;
  if (c < 32) {
    acc = b_np[c];
    #pragma unroll
    for (int k = 0; k < 6; ++k) acc += np_[(size_t)node * 6 + k] * w_np[k * 32 + c];
    col = 64 + c;
  } else {
    int cc = c - 32;
    acc = b_cp[cc];
    #pragma unroll
    for (int k = 0; k < 11; ++k) acc += cp[(size_t)node * 11 + k] * w_cp[k * 32 + cc];
    col = 96 + cc;
  }
  x0[(size_t)node * 128 + col] = f2bf(leaky(acc, 0.01f));
}

// ---------------------------------------------------------------------------
// Fused: x = leaky(x0@w_in + b_in)  [kept in per-wave LDS, never global]
//        h1 = x @ g1_w              [written bf16]
//        a_s/a_d = att dots (H=4)   [in-register + 16-lane shfl reduce]
// ---------------------------------------------------------------------------
__global__ __launch_bounds__(256) void h1_fused_kernel(
    const unsigned short* __restrict__ X, const short* __restrict__ sw_in,
    const float* __restrict__ b_in, const short* __restrict__ sw_g1,
    const float* __restrict__ att_s, const float* __restrict__ att_d,
    unsigned short* __restrict__ H1, float* __restrict__ a_s,
    float* __restrict__ a_d, int n_rows) {
  __shared__ char xt[4 * 4096];
  int wv = threadIdx.x >> 6, lane = threadIdx.x & 63;
  int row0 = blockIdx.x * 64 + wv * 16;
  int rA = row0 + (lane & 15);
  int rc = rA < n_rows ? rA : (n_rows - 1);
  const unsigned short* xr = X + (size_t)rc * 128 + (lane >> 4) * 8;
  int quad = lane >> 4, cl = lane & 15;
  char* xw = xt + wv * 4096;

  // GEMM1: x0 @ w_in
  f32x4 acc[8] = {};
  #pragma unroll
  for (int ks = 0; ks < 4; ++ks) {
    bf16x8 af = *(const bf16x8*)(xr + ks * 32);
    #pragma unroll
    for (int ct = 0; ct < 8; ++ct) {
      bf16x8 bfr = *(const bf16x8*)&sw_in[(size_t)((ks * 8 + ct) * 64 + lane) * 8];
      acc[ct] = __builtin_amdgcn_mfma_f32_16x16x32_bf16(af, bfr, acc[ct], 0, 0, 0);
    }
  }
  // bias + leaky, stash x-tile to LDS (swizzled)
  #pragma unroll
  for (int r = 0; r < 4; ++r) {
    int lr = quad * 4 + r;
    #pragma unroll
    for (int ct = 0; ct < 8; ++ct) {
      float v = leaky(acc[ct][r] + b_in[ct * 16 + cl], 0.01f);
      int cb = (ct * 32 + cl * 2) ^ ((lr & 7) << 4);
      *(unsigned short*)(xw + lr * 256 + cb) = f2bf(v);
    }
  }
  // GEMM2: x @ g1_w
  f32x4 acc2[8] = {};
  int lr2 = lane & 15;
  #pragma unroll
  for (int ks = 0; ks < 4; ++ks) {
    int cb0 = (((lane >> 4) * 16 + ks * 64)) ^ ((lr2 & 7) << 4);
    bf16x8 af = *(const bf16x8*)(xw + lr2 * 256 + cb0);
    #pragma unroll
    for (int ct = 0; ct < 8; ++ct) {
      bf16x8 bfr = *(const bf16x8*)&sw_g1[(size_t)((ks * 8 + ct) * 64 + lane) * 8];
      acc2[ct] = __builtin_amdgcn_mfma_f32_16x16x32_bf16(af, bfr, acc2[ct], 0, 0, 0);
    }
  }
  // epilogue: write h1 + att dots (head = col>>5 = ct>>1)
  float asv[8], adv[8];
  #pragma unroll
  for (int ct = 0; ct < 8; ++ct) {
    int idx = (ct >> 1) * 32 + (ct & 1) * 16 + cl;
    asv[ct] = att_s[idx];
    adv[ct] = att_d[idx];
  }
  #pragma unroll
  for (int r = 0; r < 4; ++r) {
    int row = row0 + quad * 4 + r;
    bool ok = row < n_rows;
    if (ok) {
      #pragma unroll
      for (int ct = 0; ct < 8; ++ct)
        H1[(size_t)row * 128 + ct * 16 + cl] = f2bf(acc2[ct][r]);
    }
    #pragma unroll
    for (int h = 0; h < 4; ++h) {
      float ps = acc2[2 * h][r] * asv[2 * h] + acc2[2 * h + 1][r] * asv[2 * h + 1];
      float pd = acc2[2 * h][r] * adv[2 * h] + acc2[2 * h + 1][r] * adv[2 * h + 1];
      ps = red16(ps); pd = red16(pd);
      if (ok && cl == 0) {
        a_s[(size_t)row * 4 + h] = ps;
        a_d[(size_t)row * 4 + h] = pd;
      }
    }
  }
}

// ---------------------------------------------------------------------------
// Fused: h2 = x1 @ g2_w (no bias/act) + att dots (H=1)
// ---------------------------------------------------------------------------
__global__ __launch_bounds__(256) void h2_fused_kernel(
    const unsigned short* __restrict__ X, const short* __restrict__ Wsw,
    const float* __restrict__ att_s, const float* __restrict__ att_d,
    unsigned short* __restrict__ H2, float* __restrict__ a_s,
    float* __restrict__ a_d, int n_rows) {
  int wv = threadIdx.x >> 6, lane = threadIdx.x & 63;
  int row0 = blockIdx.x * 64 + wv * 16;
  int rA = row0 + (lane & 15);
  int rc = rA < n_rows ? rA : (n_rows - 1);
  const unsigned short* xr = X + (size_t)rc * 128 + (lane >> 4) * 8;
  int quad = lane >> 4, cl = lane & 15;
  f32x4 acc[8] = {};
  #pragma unroll
  for (int ks = 0; ks < 4; ++ks) {
    bf16x8 af = *(const bf16x8*)(xr + ks * 32);
    #pragma unroll
    for (int ct = 0; ct < 8; ++ct) {
      bf16x8 bfr = *(const bf16x8*)&Wsw[(size_t)((ks * 8 + ct) * 64 + lane) * 8];
      acc[ct] = __builtin_amdgcn_mfma_f32_16x16x32_bf16(af, bfr, acc[ct], 0, 0, 0);
    }
  }
  float asv[8], adv[8];
  #pragma unroll
  for (int ct = 0; ct < 8; ++ct) {
    asv[ct] = att_s[ct * 16 + cl];
    adv[ct] = att_d[ct * 16 + cl];
  }
  #pragma unroll
  for (int r = 0; r < 4; ++r) {
    int row = row0 + quad * 4 + r;
    bool ok = row < n_rows;
    float ps = 0.f, pd = 0.f;
    #pragma unroll
    for (int ct = 0; ct < 8; ++ct) {
      if (ok) H2[(size_t)row * 128 + ct * 16 + cl] = f2bf(acc[ct][r]);
      ps += acc[ct][r] * asv[ct];
      pd += acc[ct][r] * adv[ct];
    }
    ps = red16(ps); pd = red16(pd);
    if (ok && cl == 0) { a_s[row] = ps; a_d[row] = pd; }
  }
}

// ---------------------------------------------------------------------------
// Fused: t = leaky(x2 @ w_o1 + b_o1)  [registers only]
//        out = t @ w_o2 + b_o2        [128x2 dot + 16-lane reduce]
// ---------------------------------------------------------------------------
__global__ __launch_bounds__(256) void out_fused_kernel(
    const unsigned short* __restrict__ X, const short* __restrict__ Wsw,
    const float* __restrict__ bias, const float* __restrict__ w_o2,
    const float* __restrict__ b_o2, float* __restrict__ out, int n_rows) {
  int wv = threadIdx.x >> 6, lane = threadIdx.x & 63;
  int row0 = blockIdx.x * 64 + wv * 16;
  int rA = row0 + (lane & 15);
  int rc = rA < n_rows ? rA : (n_rows - 1);
  const unsigned short* xr = X + (size_t)rc * 128 + (lane >> 4) * 8;
  int quad = lane >> 4, cl = lane & 15;
  f32x4 acc[8] = {};
  #pragma unroll
  for (int ks = 0; ks < 4; ++ks) {
    bf16x8 af = *(const bf16x8*)(xr + ks * 32);
    #pragma unroll
    for (int ct = 0; ct < 8; ++ct) {
      bf16x8 bfr = *(const bf16x8*)&Wsw[(size_t)((ks * 8 + ct) * 64 + lane) * 8];
      acc[ct] = __builtin_amdgcn_mfma_f32_16x16x32_bf16(af, bfr, acc[ct], 0, 0, 0);
    }
  }
  float w0v[8], w1v[8], bv[8];
  #pragma unroll
  for (int ct = 0; ct < 8; ++ct) {
    int col = ct * 16 + cl;
    w0v[ct] = w_o2[col * 2 + 0];
    w1v[ct] = w_o2[col * 2 + 1];
    bv[ct]  = bias[col];
  }
  float ob0 = b_o2[0], ob1 = b_o2[1];
  #pragma unroll
  for (int r = 0; r < 4; ++r) {
    int row = row0 + quad * 4 + r;
    bool ok = row < n_rows;
    float p0 = 0.f, p1 = 0.f;
    #pragma unroll
    for (int ct = 0; ct < 8; ++ct) {
      float t = leaky(acc[ct][r] + bv[ct], 0.01f);
      p0 += t * w0v[ct];
      p1 += t * w1v[ct];
    }
    p0 = red16(p0); p1 = red16(p1);
    if (ok && cl == 0) {
      out[(size_t)row * 2 + 0] = p0 + ob0;
      out[(size_t)row * 2 + 1] = p1 + ob1;
    }
  }
}

// ---------------------------------------------------------------------------
// GAT aggregation, online softmax, unroll-8 deferred rescale. Wave per dst.
// (unroll 4->8: agg is latency-bound on random h-row gathers — double MLP)
// ---------------------------------------------------------------------------
template <int H>
__global__ __launch_bounds__(256) void agg_kernel(
    const ushort2* __restrict__ h2, const float* __restrict__ a_src,
    const float* __restrict__ a_dst, const int* __restrict__ offs,
    const int* __restrict__ csr_src, const float* __restrict__ bias,
    unsigned short* __restrict__ out, int n_rows) {
  int n = (blockIdx.x * 256 + threadIdx.x) >> 6;
  int lane = threadIdx.x & 63;
  if (n >= n_rows) return;
  int c = lane * 2;
  int head = (c * H) >> 7;

  float ad = a_dst[(size_t)n * H + head];
  float m = leaky(a_src[(size_t)n * H + head] + ad, 0.2f);
  float l = 1.0f;
  ushort2 hv = h2[(size_t)n * 64 + lane];
  float acc0 = bf2f(hv.x), acc1 = bf2f(hv.y);

  int e = offs[n], e1 = offs[n + 1];
  for (; e + 8 <= e1; e += 8) {
    int s[8];
    #pragma unroll
    for (int i = 0; i < 8; ++i) s[i] = csr_src[e + i];
    float a[8]; ushort2 g[8];
    #pragma unroll
    for (int i = 0; i < 8; ++i) a[i] = leaky(a_src[(size_t)s[i] * H + head] + ad, 0.2f);
    #pragma unroll
    for (int i = 0; i < 8; ++i) g[i] = h2[(size_t)s[i] * 64 + lane];
    float mn = m;
    #pragma unroll
    for (int i = 0; i < 8; ++i) mn = fmaxf(mn, a[i]);
    float sc = __expf(m - mn);
    float x[8];
    #pragma unroll
    for (int i = 0; i < 8; ++i) x[i] = __expf(a[i] - mn);
    float ls = 0.f, p0 = 0.f, p1 = 0.f;
    #pragma unroll
    for (int i = 0; i < 8; ++i) {
      ls += x[i];
      p0 += x[i] * bf2f(g[i].x);
      p1 += x[i] * bf2f(g[i].y);
    }
    l = l * sc + ls;
    acc0 = acc0 * sc + p0;
    acc1 = acc1 * sc + p1;
    m = mn;
  }
  for (; e < e1; ++e) {
    int s = csr_src[e];
    float a = leaky(a_src[(size_t)s * H + head] + ad, 0.2f);
    float mn = fmaxf(m, a);
    float sc = __expf(m - mn), ex = __expf(a - mn);
    ushort2 g = h2[(size_t)s * 64 + lane];
    l = l * sc + ex;
    acc0 = acc0 * sc + ex * bf2f(g.x);
    acc1 = acc1 * sc + ex * bf2f(g.y);
    m = mn;
  }
  float inv = 1.0f / (l + 1e-16f);
  out[(size_t)n * 128 + c]     = f2bf(acc0 * inv + bias[c]);
  out[(size_t)n * 128 + c + 1] = f2bf(acc1 * inv + bias[c + 1]);
}

// ---------------------------------------------------------------------------
static inline size_t align256(size_t x) { return (x + 255) & ~(size_t)255; }

extern "C" void kernel_launch(void* const* d_in, const int* in_sizes, int n_in,
                              void* d_out, int out_size, void* d_ws, size_t ws_size,
                              hipStream_t stream) {
  const float* des      = (const float*)d_in[0];
  const float* tweet    = (const float*)d_in[1];
  const float* num_prop = (const float*)d_in[2];
  const float* cat_prop = (const float*)d_in[3];
  const int*   ei       = (const int*)d_in[4];
  const float* w_des = (const float*)d_in[6];
  const float* b_des = (const float*)d_in[7];
  const float* w_tw  = (const float*)d_in[8];
  const float* b_tw  = (const float*)d_in[9];
  const float* w_np  = (const float*)d_in[10];
  const float* b_np  = (const float*)d_in[11];
  const float* w_cp  = (const float*)d_in[12];
  const float* b_cp  = (const float*)d_in[13];
  const float* w_in  = (const float*)d_in[14];
  const float* b_in  = (const float*)d_in[15];
  const float* g1_w  = (const float*)d_in[16];
  const float* g1_as = (const float*)d_in[17];
  const float* g1_ad = (const float*)d_in[18];
  const float* g1_b  = (const float*)d_in[19];
  const float* g2_w  = (const float*)d_in[20];
  const float* g2_as = (const float*)d_in[21];
  const float* g2_ad = (const float*)d_in[22];
  const float* g2_b  = (const float*)d_in[23];
  const float* w_o1  = (const float*)d_in[24];
  const float* b_o1  = (const float*)d_in[25];
  const float* w_o2  = (const float*)d_in[26];
  const float* b_o2  = (const float*)d_in[27];

  const int N = in_sizes[0] / 768;
  const int E = in_sizes[4] / 2;
  const int* src = ei;
  const int* dst = ei + E;

  const int NB = (N + 255) >> BSHIFT;   // buckets of 256 nodes

  // ---- workspace layout (256B aligned segments) ----
  char* p = (char*)d_ws;
  unsigned short* bufA = (unsigned short*)p; p += align256((size_t)N * 128 * 2);
  unsigned short* bufB = (unsigned short*)p; p += align256((size_t)N * 128 * 2);
  float* as1 = (float*)p; p += align256((size_t)N * 4 * 4);
  float* ad1 = (float*)p; p += align256((size_t)N * 4 * 4);
  float* as2 = (float*)p; p += align256((size_t)N * 4);
  float* ad2 = (float*)p; p += align256((size_t)N * 4);
  int* offs = (int*)p; p += align256((size_t)(N + 1) * 4);
  int* csr  = (int*)p; p += align256((size_t)E * 4);
  short* sw_des = (short*)p; p += align256(768 * 32 * 2);
  short* sw_tw  = (short*)p; p += align256(768 * 32 * 2);
  short* sw_in  = (short*)p; p += align256(128 * 128 * 2);
  short* sw_g1  = (short*)p; p += align256(128 * 128 * 2);
  short* sw_g2  = (short*)p; p += align256(128 * 128 * 2);
  short* sw_o1  = (short*)p; p += align256(128 * 128 * 2);

  // CSR-build scratch aliases bufA/bufB (dead until encoders write them).
  int* pairs = (int*)bufA;                       // E*4 <= N*256 bytes
  char* q = (char*)bufB;
  int* blkcnt = (int*)q; q += align256((size_t)NBLK * NB * 4);
  int* blkoff = (int*)q; q += align256((size_t)NBLK * NB * 4);
  int* sbkt   = (int*)q; q += align256((size_t)(NB + 1) * 4);

  // ---- weight swizzle (tiny) ----
  dim3 gswz(12, 6);
  swz_kernel<<<gswz, 256, 0, stream>>>(w_des, w_tw, w_in, g1_w, g2_w, w_o1,
                                       sw_des, sw_tw, sw_in, sw_g1, sw_g2, sw_o1);

  // ---- CSR build (no global atomics, no memset) ----
  csr_hist_kernel<<<NBLK, 256, 0, stream>>>(dst, blkcnt, NB, E);
  csr_scan_kernel<<<1, 1024, 0, stream>>>(blkcnt, blkoff, sbkt, NB);
  csr_scatter_kernel<<<NBLK, 256, 0, stream>>>(src, dst, blkoff, pairs, NB, E);
  bkt_build_kernel<<<NB, 256, 0, stream>>>(sbkt, pairs, offs, csr, N, NB);

  // ---- encoders -> bufA = x0 (bf16) ----
  dim3 genc((N + 31) / 32, 2);
  enc_lds_kernel<<<genc, 256, 0, stream>>>(des, tweet, sw_des, sw_tw, b_des, b_tw, bufA, N);
  enc_small_kernel<<<((size_t)N * 64 + 255) / 256, 256, 0, stream>>>(
      num_prop, cat_prop, w_np, w_cp, b_np, b_cp, bufA, N);

  int gd = (N + 63) / 64;
  int gw = ((size_t)N * 64 + 255) / 256;   // one wave per node

  // ---- GAT1: x = leaky(x0@w_in+b_in) -> h1 = x@g1_w (+dots) -> bufB ----
  h1_fused_kernel<<<gd, 256, 0, stream>>>(bufA, sw_in, b_in, sw_g1,
                                          g1_as, g1_ad, bufB, as1, ad1, N);
  agg_kernel<4><<<gw, 256, 0, stream>>>((const ushort2*)bufB, as1, ad1, offs, csr, g1_b, bufA, N); // x1

  // ---- GAT2: h2 = x1@g2_w (+dots) -> bufB ----
  h2_fused_kernel<<<gd, 256, 0, stream>>>(bufA, sw_g2, g2_as, g2_ad, bufB, as2, ad2, N);
  agg_kernel<1><<<gw, 256, 0, stream>>>((const ushort2*)bufB, as2, ad2, offs, csr, g2_b, bufA, N); // x2

  // ---- output MLP: t = leaky(x2@w_o1+b_o1); out = t@w_o2+b_o2 ----
  out_fused_kernel<<<gd, 256, 0, stream>>>(bufA, sw_o1, b_o1, w_o2, b_o2, (float*)d_out, N);
}